// Round 17
// baseline (1102.742 us; speedup 1.0000x reference)
//
#include <hip/hip_runtime.h>
#include <cstdint>
#include <cstddef>

// GRAN mixture-Bernoulli forward — R17: proj indirection ELIMINATED.
// Edge kernel builds DIF = state[src]-state[dst] tile in LDS (half the random
// gather bytes of proj) and runs stage1 as K=256 GEMM [DIF;EF]@W1.
// node/dec kernels lose their proj GEMM epilogues (-25.6MB writes x3, -32
// MFMAs/wave, -repack barriers). MfmaUtil was 8.8% -> compute is free.
// Sizes: N=50000, M=250000, E=200000, H=EF=ATT=128, K=20, L=3, S=512.

typedef __bf16 bf16x8 __attribute__((ext_vector_type(8)));
typedef short  s16x8  __attribute__((ext_vector_type(8)));
typedef short  s16x4  __attribute__((ext_vector_type(4)));
typedef float  f32x4  __attribute__((ext_vector_type(4)));

__device__ inline unsigned short f2bf(float f) {
    return __builtin_bit_cast(unsigned short, (__bf16)f);
}
__device__ inline float bf2f(unsigned short b) {
    return __uint_as_float(((unsigned int)b) << 16);
}
__device__ inline unsigned int pk2(float a, float b) {
    return ((unsigned int)f2bf(b) << 16) | f2bf(a);
}
__device__ inline f32x4 MFMA(bf16x8 a, bf16x8 b, f32x4 c) {
    return __builtin_amdgcn_mfma_f32_16x16x32_bf16(a, b, c, 0, 0, 0);
}

// Swizzled LDS tile: [rows][128 bf16] = 256B/row, 16B unit u stored at u^(row&7).
__device__ inline bf16x8 ld_swz(const char* lds, int row, int unit) {
    return *(const bf16x8*)(lds + row * 256 + ((unit ^ (row & 7)) << 4));
}
__device__ inline void hid_write(char* HID, int h0, int erow, s16x4 s4) {
    int unit = h0 >> 3;
    *(s16x4*)(HID + erow * 256 + ((unit ^ (erow & 7)) << 4) + ((h0 & 4) << 1)) = s4;
}
__device__ inline s16x4 ld_swz4(const char* lds, int row, int c0) {
    int unit = c0 >> 3;
    return *(const s16x4*)(lds + row * 256 + ((unit ^ (row & 7)) << 4) + ((c0 & 4) << 1));
}
__device__ inline bf16x8 ldA(const short* __restrict__ Wb, int K, int row, int koff) {
    return *(const bf16x8*)(Wb + (size_t)row * K + koff);
}
__device__ inline bf16x8 ld_f32_frag(const float* __restrict__ p) {
    float4 a = *(const float4*)p, b = *(const float4*)(p + 4);
    s16x8 s;
    s[0] = f2bf(a.x); s[1] = f2bf(a.y); s[2] = f2bf(a.z); s[3] = f2bf(a.w);
    s[4] = f2bf(b.x); s[5] = f2bf(b.y); s[6] = f2bf(b.z); s[7] = f2bf(b.w);
    return __builtin_bit_cast(bf16x8, s);
}

// ---------------------------------------------------------------------------
// Weight prepack: fp32 [rows][srcStride] -> bf16 [rowsTot][cols] (zero-pad).
// ---------------------------------------------------------------------------
#define NPACK 31
struct PrepackArgs {
    const float* src[NPACK];
    short*       dst[NPACK];
    int stride[NPACK];
    int rows[NPACK];
    int rowsTot[NPACK];
    int cols[NPACK];
};

__global__ void prepack(PrepackArgs a) {
    int e = blockIdx.y;
    int row = blockIdx.x;
    if (row >= a.rowsTot[e]) return;
    int c8 = threadIdx.x;
    if (c8 * 8 >= a.cols[e]) return;
    s16x8 s = {};
    if (row < a.rows[e]) {
        const float* p = a.src[e] + (size_t)row * a.stride[e] + c8 * 8;
        float4 x = *(const float4*)p, y = *(const float4*)(p + 4);
        s[0] = f2bf(x.x); s[1] = f2bf(x.y); s[2] = f2bf(x.z); s[3] = f2bf(x.w);
        s[4] = f2bf(y.x); s[5] = f2bf(y.y); s[6] = f2bf(y.z); s[7] = f2bf(y.w);
    }
    *(s16x8*)(a.dst[e] + (size_t)row * a.cols[e] + c8 * 8) = s;
}

// ---------------------------------------------------------------------------
// dec: state0 = node_feat @ dec_W^T + dec_b (bf16 out, coalesced via LDS).
// ---------------------------------------------------------------------------
__global__ __launch_bounds__(256, 3)
void dec_kernel(const float* __restrict__ nf, int R,
                const short* __restrict__ decWb, const float* __restrict__ bias,
                short* __restrict__ sOut)
{
    __shared__ char ST[16384];
    const int tid = threadIdx.x, l = tid & 63, w = tid >> 6;
    const int rb = blockIdx.x * 64;

    const float* brow[4];
#pragma unroll
    for (int n = 0; n < 4; ++n) {
        int row = rb + 16 * n + (l & 15); if (row >= R) row = R - 1;
        brow[n] = nf + (size_t)row * 512;
    }

    f32x4 acc[2][4] = {};
    for (int kc = 0; kc < 512; kc += 128) {
#pragma unroll
        for (int ks = 0; ks < 4; ++ks) {
            int koff = kc + ks * 32 + (l >> 4) * 8;
            bf16x8 a0 = ldA(decWb, 512, 32 * w + (l & 15), koff);
            bf16x8 a1 = ldA(decWb, 512, 32 * w + 16 + (l & 15), koff);
#pragma unroll
            for (int n = 0; n < 4; ++n) {
                bf16x8 b = ld_f32_frag(brow[n] + koff);
                acc[0][n] = MFMA(a0, b, acc[0][n]);
                acc[1][n] = MFMA(a1, b, acc[1][n]);
            }
        }
    }
#pragma unroll
    for (int mt = 0; mt < 2; ++mt) {
        int c0 = 32 * w + 16 * mt + ((l >> 4) << 2);
        float4 bv = *(const float4*)&bias[c0];
#pragma unroll
        for (int n = 0; n < 4; ++n) {
            f32x4 v = acc[mt][n];
            s16x4 s4;
            s4[0] = f2bf(v[0] + bv.x); s4[1] = f2bf(v[1] + bv.y);
            s4[2] = f2bf(v[2] + bv.z); s4[3] = f2bf(v[3] + bv.w);
            hid_write(ST, c0, 16 * n + (l & 15), s4);
        }
    }
    __syncthreads();
#pragma unroll
    for (int p2 = 0; p2 < 4; ++p2) {
        int row = p2 * 16 + (tid >> 4);
        int r = rb + row;
        if (r < R) {
            bf16x8 v = ld_swz(ST, row, tid & 15);
            *(s16x8*)(sOut + (size_t)r * 128 + (tid & 15) * 8) =
                __builtin_bit_cast(s16x8, v);
        }
    }
}

// ---------------------------------------------------------------------------
// node_fused7 (R17): CSR agg + sin staged to LDS; GRU in two rolled 32-row
// halves (unroll-1); NO proj epilogue. 48KB LDS, launch_bounds(256,3).
// ---------------------------------------------------------------------------
template<int HAS_RELU>
__global__ __launch_bounds__(256, 3)
void node_fused7(const short* __restrict__ msgatt, const int* __restrict__ rowptr,
                 const short* __restrict__ sin_,
                 const short* __restrict__ Wih, const short* __restrict__ Whh,
                 const float* __restrict__ bih, const float* __restrict__ bhh,
                 short* __restrict__ sOut, int R)
{
    __shared__ char AGT[16384];
    __shared__ char SIN[16384];
    __shared__ char ST[16384];
    const int tid = threadIdx.x, l = tid & 63, w = tid >> 6;
    const int rb = blockIdx.x * 64;

#pragma unroll 1
    for (int pass = 0; pass < 4; ++pass) {
        int row = pass * 16 + (tid >> 4);
        int node = rb + row;
        int u = tid & 15;
        float acc[8] = {};
        s16x8 sv = {};
        if (node < R) {
            int b = rowptr[node], e = rowptr[node + 1];
            for (int i = b; i < e; ++i) {
                s16x8 x = *(const s16x8*)(msgatt + (size_t)i * 128 + u * 8);
#pragma unroll
                for (int j = 0; j < 8; ++j) acc[j] += bf2f((unsigned short)x[j]);
            }
            sv = *(const s16x8*)(sin_ + (size_t)node * 128 + u * 8);
        }
        s16x8 o;
#pragma unroll
        for (int j = 0; j < 8; ++j) o[j] = f2bf(acc[j]);
        *(s16x8*)(AGT + row * 256 + ((u ^ (row & 7)) << 4)) = o;
        *(s16x8*)(SIN + row * 256 + ((u ^ (row & 7)) << 4)) = sv;
    }
    __syncthreads();

#pragma unroll 1
    for (int nh = 0; nh < 2; ++nh) {
        unsigned int rpk[2][2][2], zpk[2][2][2];
#pragma unroll 1
        for (int p = 0; p < 3; ++p) {
            f32x4 gia[2][2] = {}, gha[2][2] = {};
#pragma unroll
            for (int ks = 0; ks < 4; ++ks) {
                int koff = ks * 32 + (l >> 4) * 8;
                bf16x8 ai0 = ldA(Wih, 128, p * 128 + 32 * w + (l & 15), koff);
                bf16x8 ai1 = ldA(Wih, 128, p * 128 + 32 * w + 16 + (l & 15), koff);
                bf16x8 ah0 = ldA(Whh, 128, p * 128 + 32 * w + (l & 15), koff);
                bf16x8 ah1 = ldA(Whh, 128, p * 128 + 32 * w + 16 + (l & 15), koff);
#pragma unroll
                for (int n = 0; n < 2; ++n) {
                    int row = 32 * nh + 16 * n + (l & 15);
                    bf16x8 ba = ld_swz(AGT, row, ks * 4 + (l >> 4));
                    bf16x8 bs = ld_swz(SIN, row, ks * 4 + (l >> 4));
                    gia[0][n] = MFMA(ai0, ba, gia[0][n]);
                    gia[1][n] = MFMA(ai1, ba, gia[1][n]);
                    gha[0][n] = MFMA(ah0, bs, gha[0][n]);
                    gha[1][n] = MFMA(ah1, bs, gha[1][n]);
                }
            }
#pragma unroll
            for (int mt = 0; mt < 2; ++mt) {
                int c0 = 32 * w + 16 * mt + ((l >> 4) << 2);
                float4 bi = *(const float4*)&bih[p * 128 + c0];
                float4 bh = *(const float4*)&bhh[p * 128 + c0];
                float biv[4] = {bi.x, bi.y, bi.z, bi.w};
                float bhv[4] = {bh.x, bh.y, bh.z, bh.w};
#pragma unroll
                for (int n = 0; n < 2; ++n) {
                    int row = 32 * nh + 16 * n + (l & 15);
                    float gv[4], hv[4];
#pragma unroll
                    for (int q = 0; q < 4; ++q) {
                        gv[q] = gia[mt][n][q] + biv[q];
                        hv[q] = gha[mt][n][q] + bhv[q];
                    }
                    if (p == 0) {
                        rpk[mt][n][0] = pk2(1.f / (1.f + expf(-(gv[0] + hv[0]))),
                                            1.f / (1.f + expf(-(gv[1] + hv[1]))));
                        rpk[mt][n][1] = pk2(1.f / (1.f + expf(-(gv[2] + hv[2]))),
                                            1.f / (1.f + expf(-(gv[3] + hv[3]))));
                    } else if (p == 1) {
                        zpk[mt][n][0] = pk2(1.f / (1.f + expf(-(gv[0] + hv[0]))),
                                            1.f / (1.f + expf(-(gv[1] + hv[1]))));
                        zpk[mt][n][1] = pk2(1.f / (1.f + expf(-(gv[2] + hv[2]))),
                                            1.f / (1.f + expf(-(gv[3] + hv[3]))));
                    } else {
                        s16x4 sv = ld_swz4(SIN, row, c0);
                        s16x4 s4;
#pragma unroll
                        for (int q = 0; q < 4; ++q) {
                            unsigned int ru = rpk[mt][n][q >> 1], zu = zpk[mt][n][q >> 1];
                            float r = bf2f((unsigned short)((q & 1) ? (ru >> 16) : (ru & 0xffffu)));
                            float z = bf2f((unsigned short)((q & 1) ? (zu >> 16) : (zu & 0xffffu)));
                            float nn = tanhf(gv[q] + r * hv[q]);
                            float o = (1.f - z) * nn + z * bf2f((unsigned short)sv[q]);
                            s4[q] = f2bf(HAS_RELU ? fmaxf(o, 0.f) : o);
                        }
                        hid_write(ST, c0, row, s4);
                    }
                }
            }
        }
    }
    __syncthreads();
#pragma unroll
    for (int p2 = 0; p2 < 4; ++p2) {
        int row = p2 * 16 + (tid >> 4);
        int r = rb + row;
        if (r < R) {
            bf16x8 v = ld_swz(ST, row, tid & 15);
            *(s16x8*)(sOut + (size_t)r * 128 + (tid & 15) * 8) =
                __builtin_bit_cast(s16x8, v);
        }
    }
}

// ---------------------------------------------------------------------------
// edge_fused7 (R17): DIF tile = state[src]-state[dst] built in LDS (random
// gather halved vs proj); stage1 = K=256 GEMM [DIF;EF]@W1 (msg+att combined);
// stage2 + sigmoid-mul as before. 64 edges/block, 48KB LDS, bounds(256,3).
// ---------------------------------------------------------------------------
__global__ __launch_bounds__(256, 3)
void edge_fused7(const short* __restrict__ efc,
                 const int* __restrict__ srcs, const int* __restrict__ dsts,
                 const short* __restrict__ state,   // N x 128 bf16 (relu'd for l>0)
                 const short* __restrict__ mW1a, const short* __restrict__ mW1b,
                 const short* __restrict__ mW2,
                 const short* __restrict__ aW1a, const short* __restrict__ aW1b,
                 const short* __restrict__ aW2,
                 const float* __restrict__ mb1, const float* __restrict__ mb2,
                 const float* __restrict__ ab1, const float* __restrict__ ab2,
                 short* __restrict__ msgatt, int M, int ntiles)
{
    __shared__ char DIF[16384];
    __shared__ char HIDm[16384];
    __shared__ char HIDa[16384];
    const int tid = threadIdx.x, l = tid & 63, w = tid >> 6;
    int q = ntiles >> 3, r = ntiles & 7;
    int xcd = blockIdx.x & 7, o = blockIdx.x >> 3;
    int tile = (xcd < r ? xcd * (q + 1) : r * (q + 1) + (xcd - r) * q) + o;
    const int pb = tile * 64;

    // ---- build DIF tile: 64 rows x 16 units; src random, dst CSR-seq ----
#pragma unroll 1
    for (int i = tid; i < 64 * 16; i += 256) {
        int row = i >> 4, u = i & 15;
        int pos = pb + row; if (pos >= M) pos = M - 1;
        int sv = srcs[pos], dv = dsts[pos];
        s16x8 x = *(const s16x8*)(state + (size_t)sv * 128 + u * 8);
        s16x8 y = *(const s16x8*)(state + (size_t)dv * 128 + u * 8);
        s16x8 d;
#pragma unroll
        for (int j = 0; j < 8; ++j)
            d[j] = f2bf(bf2f((unsigned short)x[j]) - bf2f((unsigned short)y[j]));
        *(s16x8*)(DIF + row * 256 + ((u ^ (row & 7)) << 4)) = d;
    }
    __syncthreads();

    const char* erow[4];
#pragma unroll
    for (int n = 0; n < 4; ++n) {
        int pos = pb + 16 * n + (l & 15); if (pos >= M) pos = M - 1;
        erow[n] = (const char*)(efc + (size_t)pos * 128);
    }

    // ---- stage 1: [DIF;EF] @ W1 (K=256), msg+att combined ----
    f32x4 accm[2][4] = {}, acca[2][4] = {};
#pragma unroll
    for (int ks = 0; ks < 4; ++ks) {          // K-half A: DIF @ W1a
        int koff = ks * 32 + (l >> 4) * 8;
        bf16x8 am0 = ldA(mW1a, 128, 32 * w + (l & 15), koff);
        bf16x8 am1 = ldA(mW1a, 128, 32 * w + 16 + (l & 15), koff);
        bf16x8 aa0 = ldA(aW1a, 128, 32 * w + (l & 15), koff);
        bf16x8 aa1 = ldA(aW1a, 128, 32 * w + 16 + (l & 15), koff);
#pragma unroll
        for (int n = 0; n < 4; ++n) {
            bf16x8 b = ld_swz(DIF, 16 * n + (l & 15), ks * 4 + (l >> 4));
            accm[0][n] = MFMA(am0, b, accm[0][n]);
            accm[1][n] = MFMA(am1, b, accm[1][n]);
            acca[0][n] = MFMA(aa0, b, acca[0][n]);
            acca[1][n] = MFMA(aa1, b, acca[1][n]);
        }
    }
#pragma unroll
    for (int ks = 0; ks < 4; ++ks) {          // K-half B: EF @ W1b
        int koff = ks * 32 + (l >> 4) * 8;
        bf16x8 am0 = ldA(mW1b, 128, 32 * w + (l & 15), koff);
        bf16x8 am1 = ldA(mW1b, 128, 32 * w + 16 + (l & 15), koff);
        bf16x8 aa0 = ldA(aW1b, 128, 32 * w + (l & 15), koff);
        bf16x8 aa1 = ldA(aW1b, 128, 32 * w + 16 + (l & 15), koff);
#pragma unroll
        for (int n = 0; n < 4; ++n) {
            bf16x8 b = *(const bf16x8*)(erow[n] + koff * 2);
            accm[0][n] = MFMA(am0, b, accm[0][n]);
            accm[1][n] = MFMA(am1, b, accm[1][n]);
            acca[0][n] = MFMA(aa0, b, acca[0][n]);
            acca[1][n] = MFMA(aa1, b, acca[1][n]);
        }
    }
    // epilogue 1: + b1, relu -> HID tiles
#pragma unroll
    for (int mt = 0; mt < 2; ++mt) {
        int h0 = 32 * w + 16 * mt + ((l >> 4) << 2);
        float4 bm = *(const float4*)&mb1[h0];
        float4 ba = *(const float4*)&ab1[h0];
        float bmv[4] = {bm.x, bm.y, bm.z, bm.w};
        float bav[4] = {ba.x, ba.y, ba.z, ba.w};
#pragma unroll
        for (int n = 0; n < 4; ++n) {
            f32x4 vm = accm[mt][n], va = acca[mt][n];
            s16x4 sm, sa;
#pragma unroll
            for (int qq = 0; qq < 4; ++qq) {
                sm[qq] = f2bf(fmaxf(vm[qq] + bmv[qq], 0.f));
                sa[qq] = f2bf(fmaxf(va[qq] + bav[qq], 0.f));
            }
            hid_write(HIDm, h0, 16 * n + (l & 15), sm);
            hid_write(HIDa, h0, 16 * n + (l & 15), sa);
        }
    }
    __syncthreads();

    // ---- stage 2: hid @ W2, sigmoid-mul, store ----
    f32x4 acc2m[2][4] = {}, acc2a[2][4] = {};
#pragma unroll
    for (int ks = 0; ks < 4; ++ks) {
        int koff = ks * 32 + (l >> 4) * 8;
        bf16x8 wm0 = ldA(mW2, 128, 32 * w + (l & 15), koff);
        bf16x8 wm1 = ldA(mW2, 128, 32 * w + 16 + (l & 15), koff);
        bf16x8 wa0 = ldA(aW2, 128, 32 * w + (l & 15), koff);
        bf16x8 wa1 = ldA(aW2, 128, 32 * w + 16 + (l & 15), koff);
#pragma unroll
        for (int n = 0; n < 4; ++n) {
            bf16x8 bm = ld_swz(HIDm, 16 * n + (l & 15), ks * 4 + (l >> 4));
            bf16x8 ba = ld_swz(HIDa, 16 * n + (l & 15), ks * 4 + (l >> 4));
            acc2m[0][n] = MFMA(wm0, bm, acc2m[0][n]);
            acc2m[1][n] = MFMA(wm1, bm, acc2m[1][n]);
            acc2a[0][n] = MFMA(wa0, ba, acc2a[0][n]);
            acc2a[1][n] = MFMA(wa1, ba, acc2a[1][n]);
        }
    }
    __syncthreads();                // HID reads done; reuse HIDm for output
#pragma unroll
    for (int mt = 0; mt < 2; ++mt) {
        int c0 = 32 * w + 16 * mt + ((l >> 4) << 2);
        float4 bm2 = *(const float4*)&mb2[c0];
        float4 ba2 = *(const float4*)&ab2[c0];
#pragma unroll
        for (int n = 0; n < 4; ++n) {
            f32x4 m_ = acc2m[mt][n], a_ = acc2a[mt][n];
            float o0 = (m_[0] + bm2.x) / (1.f + expf(-(a_[0] + ba2.x)));
            float o1 = (m_[1] + bm2.y) / (1.f + expf(-(a_[1] + ba2.y)));
            float o2 = (m_[2] + bm2.z) / (1.f + expf(-(a_[2] + ba2.z)));
            float o3 = (m_[3] + bm2.w) / (1.f + expf(-(a_[3] + ba2.w)));
            s16x4 s4;
            s4[0] = f2bf(o0); s4[1] = f2bf(o1); s4[2] = f2bf(o2); s4[3] = f2bf(o3);
            hid_write(HIDm, c0, 16 * n + (l & 15), s4);
        }
    }
    __syncthreads();
#pragma unroll
    for (int p2 = 0; p2 < 4; ++p2) {
        int row = p2 * 16 + (tid >> 4);
        int pos = pb + row;
        if (pos < M) {
            bf16x8 v = ld_swz(HIDm, row, tid & 15);
            *(s16x8*)(msgatt + (size_t)pos * 128 + (tid & 15) * 8) =
                __builtin_bit_cast(s16x8, v);
        }
    }
}

// ---------------------------------------------------------------------------
// mlp_loss (R10 hybrid — measured best): 64 edges/block, sequential passes,
// shfl-reduced loss accumulation + ballot counts.
// ---------------------------------------------------------------------------
__global__ __launch_bounds__(256, 4)
void mlp_loss(const short* __restrict__ sP, const int* __restrict__ gidx,
              const float* __restrict__ label, const int* __restrict__ sg,
              const short* __restrict__ thW1, const short* __restrict__ thW2,
              const short* __restrict__ thW3,
              const float* __restrict__ thb1, const float* __restrict__ thb2,
              const float* __restrict__ thb3,
              const short* __restrict__ alW1, const short* __restrict__ alW2,
              const short* __restrict__ alW3,
              const float* __restrict__ alb1, const float* __restrict__ alb2,
              const float* __restrict__ alb3,
              float* __restrict__ radj, float* __restrict__ rla,
              float* __restrict__ cntS, int E, int S)
{
    __shared__ char D2T[16384];
    __shared__ char HID[16384];
    __shared__ float sacc[2][2][20];
    __shared__ float scnt[2];
    __shared__ int sbase;
    const int tid = threadIdx.x, l = tid & 63, w = tid >> 6;
    const int eb = blockIdx.x * 64;

    if (tid == 0) sbase = sg[eb];
    if (tid < 80) sacc[tid / 40][(tid / 20) & 1][tid % 20] = 0.f;

    if (w == 0) {
        int e = eb + l;
        bool valid = e < E;
        int lsv = valid ? sg[e] - sg[eb] : -1;
        unsigned long long m0 = __ballot(lsv == 0);
        unsigned long long m1 = __ballot(lsv == 1);
        if (l == 0) { scnt[0] = (float)__popcll(m0); scnt[1] = (float)__popcll(m1); }
    }

    for (int i = tid; i < 64 * 16; i += 256) {
        int row = i >> 4, u = i & 15;
        int e = eb + row; if (e >= E) e = E - 1;
        int2 ab = *(const int2*)&gidx[2 * (size_t)e];
        s16x8 x = *(const s16x8*)(sP + (size_t)ab.x * 128 + u * 8);
        s16x8 y = *(const s16x8*)(sP + (size_t)ab.y * 128 + u * 8);
        s16x8 d;
#pragma unroll
        for (int j = 0; j < 8; ++j)
            d[j] = f2bf(bf2f((unsigned short)x[j]) - bf2f((unsigned short)y[j]));
        *(s16x8*)(D2T + row * 256 + ((u ^ (row & 7)) << 4)) = d;
    }
    __syncthreads();

#pragma unroll 1
    for (int pass = 0; pass < 2; ++pass) {
        const short* W1 = pass ? alW1 : thW1;
        const short* W2 = pass ? alW2 : thW2;
        const short* W3 = pass ? alW3 : thW3;
        const float* b1 = pass ? alb1 : thb1;
        const float* b2 = pass ? alb2 : thb2;
        const float* b3 = pass ? alb3 : thb3;

        f32x4 acc[2][4] = {};
#pragma unroll
        for (int ks = 0; ks < 4; ++ks) {
            int koff = ks * 32 + (l >> 4) * 8;
            bf16x8 a0 = ldA(W1, 128, 32 * w + (l & 15), koff);
            bf16x8 a1 = ldA(W1, 128, 32 * w + 16 + (l & 15), koff);
#pragma unroll
            for (int n = 0; n < 4; ++n) {
                bf16x8 b = ld_swz(D2T, 16 * n + (l & 15), ks * 4 + (l >> 4));
                acc[0][n] = MFMA(a0, b, acc[0][n]);
                acc[1][n] = MFMA(a1, b, acc[1][n]);
            }
        }
        __syncthreads();
#pragma unroll
        for (int mt = 0; mt < 2; ++mt) {
            int h0 = 32 * w + 16 * mt + ((l >> 4) << 2);
            float4 bv = *(const float4*)&b1[h0];
#pragma unroll
            for (int n = 0; n < 4; ++n) {
                f32x4 v = acc[mt][n];
                s16x4 s4;
                s4[0] = f2bf(fmaxf(v[0] + bv.x, 0.f));
                s4[1] = f2bf(fmaxf(v[1] + bv.y, 0.f));
                s4[2] = f2bf(fmaxf(v[2] + bv.z, 0.f));
                s4[3] = f2bf(fmaxf(v[3] + bv.w, 0.f));
                hid_write(HID, h0, 16 * n + (l & 15), s4);
            }
        }
        __syncthreads();
        f32x4 acc2[2][4] = {};
#pragma unroll
        for (int ks = 0; ks < 4; ++ks) {
            int koff = ks * 32 + (l >> 4) * 8;
            bf16x8 a0 = ldA(W2, 128, 32 * w + (l & 15), koff);
            bf16x8 a1 = ldA(W2, 128, 32 * w + 16 + (l & 15), koff);
#pragma unroll
            for (int n = 0; n < 4; ++n) {
                bf16x8 b = ld_swz(HID, 16 * n + (l & 15), ks * 4 + (l >> 4));
                acc2[0][n] = MFMA(a0, b, acc2[0][n]);
                acc2[1][n] = MFMA(a1, b, acc2[1][n]);
            }
        }
        __syncthreads();
#pragma unroll
        for (int mt = 0; mt < 2; ++mt) {
            int h0 = 32 * w + 16 * mt + ((l >> 4) << 2);
            float4 bv = *(const float4*)&b2[h0];
#pragma unroll
            for (int n = 0; n < 4; ++n) {
                f32x4 v = acc2[mt][n];
                s16x4 s4;
                s4[0] = f2bf(fmaxf(v[0] + bv.x, 0.f));
                s4[1] = f2bf(fmaxf(v[1] + bv.y, 0.f));
                s4[2] = f2bf(fmaxf(v[2] + bv.z, 0.f));
                s4[3] = f2bf(fmaxf(v[3] + bv.w, 0.f));
                hid_write(HID, h0, 16 * n + (l & 15), s4);
            }
        }
        __syncthreads();
        f32x4 acc3[2] = {};
#pragma unroll
        for (int ks = 0; ks < 4; ++ks) {
            int koff = ks * 32 + (l >> 4) * 8;
            bf16x8 a0 = ldA(W3, 128, (l & 15), koff);
            bf16x8 a1 = ldA(W3, 128, 16 + (l & 15), koff);
            bf16x8 b = ld_swz(HID, 16 * w + (l & 15), ks * 4 + (l >> 4));
            acc3[0] = MFMA(a0, b, acc3[0]);
            acc3[1] = MFMA(a1, b, acc3[1]);
        }
        {
            int e = eb + 16 * w + (l & 15);
            bool val = e < E;
            float lsf = val ? (float)(sg[e] - sbase) : 0.f;
            float yv = (pass == 0 && val) ? label[e] : 0.f;
#pragma unroll
            for (int mt = 0; mt < 2; ++mt) {
#pragma unroll
                for (int qq = 0; qq < 4; ++qq) {
                    int k = 16 * mt + ((l >> 4) << 2) + qq;
                    bool kok = k < 20;
                    float bk = kok ? b3[k] : 0.f;
                    float vv = 0.f;
                    if (val && kok) {
                        float t = acc3[mt][qq] + bk;
                        if (pass == 0) {
                            float sp = fmaxf(-t, 0.f) + log1pf(expf(-fabsf(t)));
                            vv = sp + (1.f - yv) * t;
                        } else {
                            vv = t;
                        }
                    }
                    float vA = vv * (1.f - lsf), vB = vv * lsf;
                    vA += __shfl_xor(vA, 1); vB += __shfl_xor(vB, 1);
                    vA += __shfl_xor(vA, 2); vB += __shfl_xor(vB, 2);
                    vA += __shfl_xor(vA, 4); vB += __shfl_xor(vB, 4);
                    vA += __shfl_xor(vA, 8); vB += __shfl_xor(vB, 8);
                    if ((l & 15) == 0 && kok) {
                        atomicAdd(&sacc[pass][0][k], vA);
                        if (vB != 0.f) atomicAdd(&sacc[pass][1][k], vB);
                    }
                }
            }
        }
    }
    __syncthreads();
    if (tid < 40) {
        int ls = tid / 20, k = tid % 20;
        int s = sbase + ls;
        if (s < S) {
            float v  = sacc[0][ls][k];
            float v2 = sacc[1][ls][k];
            if (v  != 0.f) atomicAdd(&radj[s * 20 + k], v);
            if (v2 != 0.f) atomicAdd(&rla[s * 20 + k], v2);
        }
    }
    if (tid < 2) {
        int s = sbase + tid;
        if (s < S && scnt[tid] != 0.f) atomicAdd(&cntS[s], scnt[tid]);
    }
}

// ---------------------------------------------------------------------------
// CSR build + gathers
// ---------------------------------------------------------------------------
__global__ void csr_count(const int* __restrict__ edge, int* __restrict__ cnt, int M) {
    int e = blockIdx.x * 256 + threadIdx.x;
    if (e < M) atomicAdd(&cnt[edge[2 * (size_t)e + 1]], 1);
}

__global__ void csr_scan(const int* __restrict__ cnt, int* __restrict__ rowptr,
                         int* __restrict__ wofs, int N)
{
    __shared__ int part[1024];
    int t = threadIdx.x;
    int chunk = (N + 1023) / 1024;
    int b0 = t * chunk, b1 = b0 + chunk; if (b1 > N) b1 = N; if (b0 > N) b0 = N;
    int s = 0;
    for (int i = b0; i < b1; ++i) s += cnt[i];
    part[t] = s;
    __syncthreads();
    for (int off = 1; off < 1024; off <<= 1) {
        int v = (t >= off) ? part[t - off] : 0;
        __syncthreads();
        part[t] += v;
        __syncthreads();
    }
    int run = (t ? part[t - 1] : 0);
    for (int i = b0; i < b1; ++i) { rowptr[i] = run; wofs[i] = run; run += cnt[i]; }
    if (t == 1023) rowptr[N] = run;
}

__global__ void csr_scatter2(const int* __restrict__ edge, int* __restrict__ wofs,
                             int* __restrict__ eidx, int* __restrict__ srcs,
                             int* __restrict__ dsts, int M)
{
    int e = blockIdx.x * 256 + threadIdx.x;
    if (e < M) {
        int2 sd = *(const int2*)&edge[2 * (size_t)e];
        int p = atomicAdd(&wofs[sd.y], 1);
        eidx[p] = e; srcs[p] = sd.x; dsts[p] = sd.y;
    }
}

__global__ void ef_gather(const float* __restrict__ ef, const int* __restrict__ eidx,
                          short* __restrict__ efc, int M)
{
    long i = (long)blockIdx.x * 256 + threadIdx.x;
    if (i >= (long)M * 16) return;
    int p = (int)(i >> 4), u = (int)(i & 15);
    int e = eidx[p];
    const float* sp = ef + (size_t)e * 128 + u * 8;
    float4 a = *(const float4*)sp, b = *(const float4*)(sp + 4);
    s16x8 s;
    s[0] = f2bf(a.x); s[1] = f2bf(a.y); s[2] = f2bf(a.z); s[3] = f2bf(a.w);
    s[4] = f2bf(b.x); s[5] = f2bf(b.y); s[6] = f2bf(b.z); s[7] = f2bf(b.w);
    *(s16x8*)(efc + (size_t)p * 128 + u * 8) = s;
}

// ---------------------------------------------------------------------------
__global__ void final_kernel(const float* __restrict__ radj, const float* __restrict__ rla,
                             const float* __restrict__ cnt, const int* __restrict__ bc_idx,
                             float* __restrict__ out)
{
    __shared__ float bcl[16], bcc[16];
    const int s = threadIdx.x;
    if (s < 16) { bcl[s] = 0.f; bcc[s] = 0.f; }
    __syncthreads();
    float c = cnt[s];
    float x[20];
    float mx = -1e30f;
#pragma unroll
    for (int k = 0; k < 20; ++k) { x[k] = rla[s * 20 + k] / c; mx = fmaxf(mx, x[k]); }
    float se = 0.f;
#pragma unroll
    for (int k = 0; k < 20; ++k) se += expf(x[k] - mx);
    float lse = mx + logf(se);
    float t[20];
    float m2 = -1e30f;
#pragma unroll
    for (int k = 0; k < 20; ++k) { t[k] = -radj[s * 20 + k] + x[k] - lse; m2 = fmaxf(m2, t[k]); }
    float s2 = 0.f;
#pragma unroll
    for (int k = 0; k < 20; ++k) s2 += expf(t[k] - m2);
    float lp = m2 + logf(s2);
    atomicAdd(&bcl[bc_idx[s]], lp);
    atomicAdd(&bcc[bc_idx[s]], c);
    __syncthreads();
    if (s == 0) {
        float a = 0.f;
        for (int b = 0; b < 16; ++b) a += bcl[b] / bcc[b];
        out[0] = -a / 16.f;
    }
}

// ---------------------------------------------------------------------------
extern "C" void kernel_launch(void* const* d_in, const int* in_sizes, int n_in,
                              void* d_out, int out_size, void* d_ws, size_t ws_size,
                              hipStream_t stream)
{
    const float* node_feat = (const float*)d_in[0];
    const int*   edge      = (const int*)  d_in[1];
    const float* edge_feat = (const float*)d_in[2];
    const int*   gnn_idx   = (const int*)  d_in[3];
    const float* label     = (const float*)d_in[4];
    const int*   sg_idx    = (const int*)  d_in[5];
    const int*   bc_idx    = (const int*)  d_in[6];
    const float* dec_W  = (const float*)d_in[7];
    const float* dec_b  = (const float*)d_in[8];
    const float* msg_W1 = (const float*)d_in[9];
    const float* msg_b1 = (const float*)d_in[10];
    const float* msg_W2 = (const float*)d_in[11];
    const float* msg_b2 = (const float*)d_in[12];
    const float* att_W1 = (const float*)d_in[13];
    const float* att_b1 = (const float*)d_in[14];
    const float* att_W2 = (const float*)d_in[15];
    const float* att_b2 = (const float*)d_in[16];
    const float* gru_Wih = (const float*)d_in[17];
    const float* gru_bih = (const float*)d_in[18];
    const float* gru_Whh = (const float*)d_in[19];
    const float* gru_bhh = (const float*)d_in[20];
    const float* th_W1 = (const float*)d_in[21];
    const float* th_b1 = (const float*)d_in[22];
    const float* th_W2 = (const float*)d_in[23];
    const float* th_b2 = (const float*)d_in[24];
    const float* th_W3 = (const float*)d_in[25];
    const float* th_b3 = (const float*)d_in[26];
    const float* al_W1 = (const float*)d_in[27];
    const float* al_b1 = (const float*)d_in[28];
    const float* al_W2 = (const float*)d_in[29];
    const float* al_b2 = (const float*)d_in[30];
    const float* al_W3 = (const float*)d_in[31];
    const float* al_b3 = (const float*)d_in[32];

    const int N = in_sizes[0] / 512;
    const int M = in_sizes[1] / 2;
    const int E = in_sizes[3] / 2;
    const int S = in_sizes[6];

    size_t off = 0;
    auto alloc = [&](size_t bytes) {
        char* p = (char*)d_ws + off;
        off += (bytes + 255) & ~(size_t)255;
        return p;
    };
    // bf16 weight slabs
    short* decWb  = (short*)alloc((size_t)128 * 512 * 2);
    short* mW1aB  = (short*)alloc((size_t)3 * 128 * 128 * 2);
    short* aW1aB  = (short*)alloc((size_t)3 * 128 * 128 * 2);
    short* mW1bB  = (short*)alloc((size_t)3 * 128 * 128 * 2);
    short* aW1bB  = (short*)alloc((size_t)3 * 128 * 128 * 2);
    short* mW2B   = (short*)alloc((size_t)3 * 128 * 128 * 2);
    short* aW2B   = (short*)alloc((size_t)3 * 128 * 128 * 2);
    short* gihB   = (short*)alloc((size_t)3 * 384 * 128 * 2);
    short* ghhB   = (short*)alloc((size_t)3 * 384 * 128 * 2);
    short* thW1B  = (short*)alloc((size_t)128 * 128 * 2);
    short* thW2B  = (short*)alloc((size_t)128 * 128 * 2);
    short* thW3B  = (short*)alloc((size_t)32 * 128 * 2);
    short* alW1B  = (short*)alloc((size_t)128 * 128 * 2);
    short* alW2B  = (short*)alloc((size_t)128 * 128 * 2);
    short* alW3B  = (short*)alloc((size_t)32 * 128 * 2);
    // activations
    short* sA     = (short*)alloc((size_t)N * 128 * 2);
    short* sB     = (short*)alloc((size_t)N * 128 * 2);
    short* sP     = (short*)alloc((size_t)N * 128 * 2);
    short* efc    = (short*)alloc((size_t)M * 128 * 2);
    short* msgatt = (short*)alloc((size_t)M * 128 * 2);
    int*   cntN   = (int*)  alloc((size_t)N * 4);
    int*   wofs   = (int*)  alloc((size_t)N * 4);
    int*   rowptr = (int*)  alloc((size_t)(N + 1) * 4);
    int*   eidx   = (int*)  alloc((size_t)M * 4);
    int*   srcs   = (int*)  alloc((size_t)M * 4);
    int*   dsts   = (int*)  alloc((size_t)M * 4);
    float* radj   = (float*)alloc((size_t)S * 20 * 4);
    float* rla    = (float*)alloc((size_t)S * 20 * 4);
    float* cntS   = (float*)alloc((size_t)S * 4);

    // ---- prepack descriptor table ----
    PrepackArgs pa;
    int ei = 0;
    auto add = [&](const float* s, short* d, int stride, int rows, int rowsTot, int cols) {
        pa.src[ei] = s; pa.dst[ei] = d; pa.stride[ei] = stride;
        pa.rows[ei] = rows; pa.rowsTot[ei] = rowsTot; pa.cols[ei] = cols; ++ei;
    };
    add(dec_W, decWb, 512, 128, 128, 512);
    for (int l = 0; l < 3; ++l) {
        add(msg_W1 + (size_t)l * 128 * 256,       mW1aB + (size_t)l * 16384, 256, 128, 128, 128);
        add(att_W1 + (size_t)l * 128 * 256,       aW1aB + (size_t)l * 16384, 256, 128, 128, 128);
        add(msg_W1 + (size_t)l * 128 * 256 + 128, mW1bB + (size_t)l * 16384, 256, 128, 128, 128);
        add(att_W1 + (size_t)l * 128 * 256 + 128, aW1bB + (size_t)l * 16384, 256, 128, 128, 128);
        add(msg_W2 + (size_t)l * 16384,           mW2B + (size_t)l * 16384,  128, 128, 128, 128);
        add(att_W2 + (size_t)l * 16384,           aW2B + (size_t)l * 16384,  128, 128, 128, 128);
        add(gru_Wih + (size_t)l * 49152,          gihB + (size_t)l * 49152,  128, 384, 384, 128);
        add(gru_Whh + (size_t)l * 49152,          ghhB + (size_t)l * 49152,  128, 384, 384, 128);
    }
    add(th_W1, thW1B, 128, 128, 128, 128);
    add(th_W2, thW2B, 128, 128, 128, 128);
    add(th_W3, thW3B, 128, 20, 32, 128);
    add(al_W1, alW1B, 128, 128, 128, 128);
    add(al_W2, alW2B, 128, 128, 128, 128);
    add(al_W3, alW3B, 128, 20, 32, 128);

    const dim3 blk(256);
    const int gN64 = (N + 63) / 64;
    const int gE64 = (E + 63) / 64;
    const int gMt  = (M + 255) / 256;
    const int ntilesM = (M + 63) / 64;

    hipMemsetAsync(radj, 0, (size_t)(S * 20 * 2 + S) * 4, stream);
    hipMemsetAsync(cntN, 0, (size_t)N * 4, stream);

    prepack<<<dim3(384, NPACK), dim3(64), 0, stream>>>(pa);

    csr_count   <<<gMt, blk, 0, stream>>>(edge, cntN, M);
    csr_scan    <<<1, 1024, 0, stream>>>(cntN, rowptr, wofs, N);
    csr_scatter2<<<gMt, blk, 0, stream>>>(edge, wofs, eidx, srcs, dsts, M);
    ef_gather   <<<(int)(((long)M * 16 + 255) / 256), blk, 0, stream>>>(edge_feat, eidx, efc, M);

    // decoder
    dec_kernel<<<gN64, blk, 0, stream>>>(node_feat, N, decWb, dec_b, sA);

    short* bufs[2] = { sA, sB };
    for (int l = 0; l < 3; ++l) {
        short* sin  = bufs[l & 1];
        short* sout = (l == 2) ? sP : bufs[(l + 1) & 1];
        edge_fused7<<<ntilesM, blk, 0, stream>>>(efc, srcs, dsts, sin,
            mW1aB + (size_t)l * 16384, mW1bB + (size_t)l * 16384, mW2B + (size_t)l * 16384,
            aW1aB + (size_t)l * 16384, aW1bB + (size_t)l * 16384, aW2B + (size_t)l * 16384,
            msg_b1 + l * 128, msg_b2 + l * 128,
            att_b1 + l * 128, att_b2 + l * 128,
            msgatt, M, ntilesM);
        if (l < 2) {
            node_fused7<1><<<gN64, blk, 0, stream>>>(msgatt, rowptr, sin,
                gihB + (size_t)l * 49152, ghhB + (size_t)l * 49152,
                gru_bih + l * 384, gru_bhh + l * 384, sout, N);
        } else {
            node_fused7<0><<<gN64, blk, 0, stream>>>(msgatt, rowptr, sin,
                gihB + (size_t)l * 49152, ghhB + (size_t)l * 49152,
                gru_bih + l * 384, gru_bhh + l * 384, sout, N);
        }
    }

    mlp_loss<<<gE64, blk, 0, stream>>>(sP, gnn_idx, label, sg_idx,
        thW1B, thW2B, thW3B, th_b1, th_b2, th_b3,
        alW1B, alW2B, alW3B, al_b1, al_b2, al_b3,
        radj, rla, cntS, E, S);
    final_kernel<<<1, S, 0, stream>>>(radj, rla, cntS, bc_idx, (float*)d_out);
}

// Round 18
// 1040.553 us; speedup vs baseline: 1.0598x; 1.0598x over previous
//
#include <hip/hip_runtime.h>
#include <cstdint>
#include <cstddef>

// GRAN mixture-Bernoulli forward — R18: exact revert to R14 (measured best,
// 1048us). R15 (edge pair-pipelining), R16 (node LDS trim), R17 (proj
// elimination) all regressed or were neutral -> R14 is the empirical optimum:
//  - edge_fused2: 64 edges/block, src-proj reg-prefetch, dst inline, bound 3
//  - node_fused4: CSR-agg fused, LDS-staged sin, GRU in 2 rolled halves
//    (#pragma unroll 1 -> no spill), proj epilogue, bound 2
//  - mlp_loss: sequential passes, shfl-reduced loss, ballot counts, bound 4
// Sizes: N=50000, M=250000, E=200000, H=EF=ATT=128, K=20, L=3, S=512.

typedef __bf16 bf16x8 __attribute__((ext_vector_type(8)));
typedef short  s16x8  __attribute__((ext_vector_type(8)));
typedef short  s16x4  __attribute__((ext_vector_type(4)));
typedef float  f32x4  __attribute__((ext_vector_type(4)));

__device__ inline unsigned short f2bf(float f) {
    return __builtin_bit_cast(unsigned short, (__bf16)f);
}
__device__ inline float bf2f(unsigned short b) {
    return __uint_as_float(((unsigned int)b) << 16);
}
__device__ inline unsigned int pk2(float a, float b) {
    return ((unsigned int)f2bf(b) << 16) | f2bf(a);
}
__device__ inline f32x4 MFMA(bf16x8 a, bf16x8 b, f32x4 c) {
    return __builtin_amdgcn_mfma_f32_16x16x32_bf16(a, b, c, 0, 0, 0);
}

// Swizzled LDS tile: [rows][128 bf16] = 256B/row, 16B unit u stored at u^(row&7).
__device__ inline bf16x8 ld_swz(const char* lds, int row, int unit) {
    return *(const bf16x8*)(lds + row * 256 + ((unit ^ (row & 7)) << 4));
}
__device__ inline void hid_write(char* HID, int h0, int erow, s16x4 s4) {
    int unit = h0 >> 3;
    *(s16x4*)(HID + erow * 256 + ((unit ^ (erow & 7)) << 4) + ((h0 & 4) << 1)) = s4;
}
__device__ inline s16x4 ld_swz4(const char* lds, int row, int c0) {
    int unit = c0 >> 3;
    return *(const s16x4*)(lds + row * 256 + ((unit ^ (row & 7)) << 4) + ((c0 & 4) << 1));
}
__device__ inline bf16x8 ldA(const short* __restrict__ Wb, int K, int row, int koff) {
    return *(const bf16x8*)(Wb + (size_t)row * K + koff);
}
__device__ inline bf16x8 ld_f32_frag(const float* __restrict__ p) {
    float4 a = *(const float4*)p, b = *(const float4*)(p + 4);
    s16x8 s;
    s[0] = f2bf(a.x); s[1] = f2bf(a.y); s[2] = f2bf(a.z); s[3] = f2bf(a.w);
    s[4] = f2bf(b.x); s[5] = f2bf(b.y); s[6] = f2bf(b.z); s[7] = f2bf(b.w);
    return __builtin_bit_cast(bf16x8, s);
}

// ---------------------------------------------------------------------------
// Weight prepack: fp32 [rows][srcStride] -> bf16 [rowsTot][cols] (zero-pad).
// ---------------------------------------------------------------------------
#define NPACK 31
struct PrepackArgs {
    const float* src[NPACK];
    short*       dst[NPACK];
    int stride[NPACK];
    int rows[NPACK];
    int rowsTot[NPACK];
    int cols[NPACK];
};

__global__ void prepack(PrepackArgs a) {
    int e = blockIdx.y;
    int row = blockIdx.x;
    if (row >= a.rowsTot[e]) return;
    int c8 = threadIdx.x;
    if (c8 * 8 >= a.cols[e]) return;
    s16x8 s = {};
    if (row < a.rows[e]) {
        const float* p = a.src[e] + (size_t)row * a.stride[e] + c8 * 8;
        float4 x = *(const float4*)p, y = *(const float4*)(p + 4);
        s[0] = f2bf(x.x); s[1] = f2bf(x.y); s[2] = f2bf(x.z); s[3] = f2bf(x.w);
        s[4] = f2bf(y.x); s[5] = f2bf(y.y); s[6] = f2bf(y.z); s[7] = f2bf(y.w);
    }
    *(s16x8*)(a.dst[e] + (size_t)row * a.cols[e] + c8 * 8) = s;
}

// ---------------------------------------------------------------------------
// Shared epilogue: proj GEMM from ST, repacked through PJ, stored coalesced to
// interleaved proj (node row = 256 shorts: [4 msg | 4 att] per 8).
// ---------------------------------------------------------------------------
__device__ inline void proj_gemm_store(const char* ST, char* PJ,
                                       const short* __restrict__ projW,
                                       short* __restrict__ proj,
                                       int rb, int R, int tid)
{
    const int l = tid & 63, w = tid >> 6;
    f32x4 accP[2][2][4] = {};
#pragma unroll
    for (int ks = 0; ks < 4; ++ks) {
        int koff = ks * 32 + (l >> 4) * 8;
        bf16x8 aw[2][2];
#pragma unroll
        for (int pc = 0; pc < 2; ++pc)
#pragma unroll
            for (int mt = 0; mt < 2; ++mt)
                aw[pc][mt] = ldA(projW, 128, pc * 128 + 32 * w + 16 * mt + (l & 15), koff);
#pragma unroll
        for (int n = 0; n < 4; ++n) {
            bf16x8 b = ld_swz(ST, 16 * n + (l & 15), ks * 4 + (l >> 4));
#pragma unroll
            for (int pc = 0; pc < 2; ++pc)
#pragma unroll
                for (int mt = 0; mt < 2; ++mt)
                    accP[pc][mt][n] = MFMA(aw[pc][mt], b, accP[pc][mt][n]);
        }
    }
    const int half = w >> 1;
#pragma unroll
    for (int hh = 0; hh < 2; ++hh) {
        __syncthreads();
        if (half == hh) {
#pragma unroll
            for (int pc = 0; pc < 2; ++pc)
#pragma unroll
                for (int mt = 0; mt < 2; ++mt) {
                    int h0 = 32 * w + 16 * mt + ((l >> 4) << 2);
                    int colp = 2 * h0 + 4 * pc - 128 * hh;
#pragma unroll
                    for (int n = 0; n < 4; ++n) {
                        f32x4 v = accP[pc][mt][n];
                        s16x4 s4;
                        s4[0] = f2bf(v[0]); s4[1] = f2bf(v[1]);
                        s4[2] = f2bf(v[2]); s4[3] = f2bf(v[3]);
                        hid_write(PJ, colp, 16 * n + (l & 15), s4);
                    }
                }
        }
        __syncthreads();
#pragma unroll
        for (int p2 = 0; p2 < 4; ++p2) {
            int row = p2 * 16 + (tid >> 4);
            int r = rb + row;
            if (r < R) {
                bf16x8 v = ld_swz(PJ, row, tid & 15);
                *(s16x8*)(proj + (size_t)r * 256 + hh * 128 + (tid & 15) * 8) =
                    __builtin_bit_cast(s16x8, v);
            }
        }
    }
}

// ---------------------------------------------------------------------------
// dec_proj: state0 = node_feat @ dec_W^T + dec_b ; proj0 = state0 @ projW^T.
// ---------------------------------------------------------------------------
__global__ __launch_bounds__(256, 3)
void dec_proj(const float* __restrict__ nf, int R,
              const short* __restrict__ decWb, const float* __restrict__ bias,
              const short* __restrict__ projW,
              short* __restrict__ sOut, short* __restrict__ proj)
{
    __shared__ char ST[16384];
    __shared__ char PJ[16384];
    const int tid = threadIdx.x, l = tid & 63, w = tid >> 6;
    const int rb = blockIdx.x * 64;

    const float* brow[4];
#pragma unroll
    for (int n = 0; n < 4; ++n) {
        int row = rb + 16 * n + (l & 15); if (row >= R) row = R - 1;
        brow[n] = nf + (size_t)row * 512;
    }

    f32x4 acc[2][4] = {};
    for (int kc = 0; kc < 512; kc += 128) {
#pragma unroll
        for (int ks = 0; ks < 4; ++ks) {
            int koff = kc + ks * 32 + (l >> 4) * 8;
            bf16x8 a0 = ldA(decWb, 512, 32 * w + (l & 15), koff);
            bf16x8 a1 = ldA(decWb, 512, 32 * w + 16 + (l & 15), koff);
#pragma unroll
            for (int n = 0; n < 4; ++n) {
                bf16x8 b = ld_f32_frag(brow[n] + koff);
                acc[0][n] = MFMA(a0, b, acc[0][n]);
                acc[1][n] = MFMA(a1, b, acc[1][n]);
            }
        }
    }
#pragma unroll
    for (int mt = 0; mt < 2; ++mt) {
        int c0 = 32 * w + 16 * mt + ((l >> 4) << 2);
        float4 bv = *(const float4*)&bias[c0];
#pragma unroll
        for (int n = 0; n < 4; ++n) {
            f32x4 v = acc[mt][n];
            s16x4 s4;
            s4[0] = f2bf(v[0] + bv.x); s4[1] = f2bf(v[1] + bv.y);
            s4[2] = f2bf(v[2] + bv.z); s4[3] = f2bf(v[3] + bv.w);
            hid_write(ST, c0, 16 * n + (l & 15), s4);
        }
    }
    __syncthreads();
#pragma unroll
    for (int p2 = 0; p2 < 4; ++p2) {
        int row = p2 * 16 + (tid >> 4);
        int r = rb + row;
        if (r < R) {
            bf16x8 v = ld_swz(ST, row, tid & 15);
            *(s16x8*)(sOut + (size_t)r * 128 + (tid & 15) * 8) =
                __builtin_bit_cast(s16x8, v);
        }
    }
    proj_gemm_store(ST, PJ, projW, proj, rb, R, tid);
}

// ---------------------------------------------------------------------------
// node_fused4 (R14): CSR agg + sin staged to LDS; GRU in TWO 32-row halves
// with #pragma unroll 1 (forces sequential halves -> no spill); proj epilogue.
// ---------------------------------------------------------------------------
template<int HAS_PROJ>
__global__ __launch_bounds__(256, 2)
void node_fused4(const short* __restrict__ msgatt, const int* __restrict__ rowptr,
                 const short* __restrict__ sin_,
                 const short* __restrict__ Wih, const short* __restrict__ Whh,
                 const float* __restrict__ bih, const float* __restrict__ bhh,
                 const short* __restrict__ projW,
                 short* __restrict__ sOut, short* __restrict__ proj, int R)
{
    __shared__ char AGT[16384];
    __shared__ char SIN[16384];
    __shared__ char ST[16384];
    __shared__ char PJ[16384];
    const int tid = threadIdx.x, l = tid & 63, w = tid >> 6;
    const int rb = blockIdx.x * 64;

#pragma unroll 1
    for (int pass = 0; pass < 4; ++pass) {
        int row = pass * 16 + (tid >> 4);
        int node = rb + row;
        int u = tid & 15;
        float acc[8] = {};
        s16x8 sv = {};
        if (node < R) {
            int b = rowptr[node], e = rowptr[node + 1];
            for (int i = b; i < e; ++i) {
                s16x8 x = *(const s16x8*)(msgatt + (size_t)i * 128 + u * 8);
#pragma unroll
                for (int j = 0; j < 8; ++j) acc[j] += bf2f((unsigned short)x[j]);
            }
            sv = *(const s16x8*)(sin_ + (size_t)node * 128 + u * 8);
        }
        s16x8 o;
#pragma unroll
        for (int j = 0; j < 8; ++j) o[j] = f2bf(acc[j]);
        *(s16x8*)(AGT + row * 256 + ((u ^ (row & 7)) << 4)) = o;
        *(s16x8*)(SIN + row * 256 + ((u ^ (row & 7)) << 4)) = sv;
    }
    __syncthreads();

#pragma unroll 1
    for (int nh = 0; nh < 2; ++nh) {
        unsigned int rpk[2][2][2], zpk[2][2][2];
#pragma unroll 1
        for (int p = 0; p < 3; ++p) {
            f32x4 gia[2][2] = {}, gha[2][2] = {};
#pragma unroll
            for (int ks = 0; ks < 4; ++ks) {
                int koff = ks * 32 + (l >> 4) * 8;
                bf16x8 ai0 = ldA(Wih, 128, p * 128 + 32 * w + (l & 15), koff);
                bf16x8 ai1 = ldA(Wih, 128, p * 128 + 32 * w + 16 + (l & 15), koff);
                bf16x8 ah0 = ldA(Whh, 128, p * 128 + 32 * w + (l & 15), koff);
                bf16x8 ah1 = ldA(Whh, 128, p * 128 + 32 * w + 16 + (l & 15), koff);
#pragma unroll
                for (int n = 0; n < 2; ++n) {
                    int row = 32 * nh + 16 * n + (l & 15);
                    bf16x8 ba = ld_swz(AGT, row, ks * 4 + (l >> 4));
                    bf16x8 bs = ld_swz(SIN, row, ks * 4 + (l >> 4));
                    gia[0][n] = MFMA(ai0, ba, gia[0][n]);
                    gia[1][n] = MFMA(ai1, ba, gia[1][n]);
                    gha[0][n] = MFMA(ah0, bs, gha[0][n]);
                    gha[1][n] = MFMA(ah1, bs, gha[1][n]);
                }
            }
#pragma unroll
            for (int mt = 0; mt < 2; ++mt) {
                int c0 = 32 * w + 16 * mt + ((l >> 4) << 2);
                float4 bi = *(const float4*)&bih[p * 128 + c0];
                float4 bh = *(const float4*)&bhh[p * 128 + c0];
                float biv[4] = {bi.x, bi.y, bi.z, bi.w};
                float bhv[4] = {bh.x, bh.y, bh.z, bh.w};
#pragma unroll
                for (int n = 0; n < 2; ++n) {
                    int row = 32 * nh + 16 * n + (l & 15);
                    float gv[4], hv[4];
#pragma unroll
                    for (int q = 0; q < 4; ++q) {
                        gv[q] = gia[mt][n][q] + biv[q];
                        hv[q] = gha[mt][n][q] + bhv[q];
                    }
                    if (p == 0) {
                        rpk[mt][n][0] = pk2(1.f / (1.f + expf(-(gv[0] + hv[0]))),
                                            1.f / (1.f + expf(-(gv[1] + hv[1]))));
                        rpk[mt][n][1] = pk2(1.f / (1.f + expf(-(gv[2] + hv[2]))),
                                            1.f / (1.f + expf(-(gv[3] + hv[3]))));
                    } else if (p == 1) {
                        zpk[mt][n][0] = pk2(1.f / (1.f + expf(-(gv[0] + hv[0]))),
                                            1.f / (1.f + expf(-(gv[1] + hv[1]))));
                        zpk[mt][n][1] = pk2(1.f / (1.f + expf(-(gv[2] + hv[2]))),
                                            1.f / (1.f + expf(-(gv[3] + hv[3]))));
                    } else {
                        s16x4 sv = ld_swz4(SIN, row, c0);
                        s16x4 s4;
#pragma unroll
                        for (int q = 0; q < 4; ++q) {
                            unsigned int ru = rpk[mt][n][q >> 1], zu = zpk[mt][n][q >> 1];
                            float r = bf2f((unsigned short)((q & 1) ? (ru >> 16) : (ru & 0xffffu)));
                            float z = bf2f((unsigned short)((q & 1) ? (zu >> 16) : (zu & 0xffffu)));
                            float nn = tanhf(gv[q] + r * hv[q]);
                            float o = (1.f - z) * nn + z * bf2f((unsigned short)sv[q]);
                            s4[q] = f2bf(HAS_PROJ ? fmaxf(o, 0.f) : o);
                        }
                        hid_write(ST, c0, row, s4);
                    }
                }
            }
        }
    }
    __syncthreads();
#pragma unroll
    for (int p2 = 0; p2 < 4; ++p2) {
        int row = p2 * 16 + (tid >> 4);
        int r = rb + row;
        if (r < R) {
            bf16x8 v = ld_swz(ST, row, tid & 15);
            *(s16x8*)(sOut + (size_t)r * 128 + (tid & 15) * 8) =
                __builtin_bit_cast(s16x8, v);
        }
    }
    if (HAS_PROJ)
        proj_gemm_store(ST, PJ, projW, proj, rb, R, tid);
}

// ---------------------------------------------------------------------------
// Fused edge MLPs (R10 version — measured best): 256 threads, 64 edges/block.
// src-proj prefetched (random); dst-proj inline (CSR-sequential, L2-hot).
// ---------------------------------------------------------------------------
__global__ __launch_bounds__(256, 3)
void edge_fused2(const short* __restrict__ efc,
                 const int* __restrict__ srcs, const int* __restrict__ dsts,
                 const short* __restrict__ proj,    // N x 256 interleaved
                 const short* __restrict__ mW1b, const short* __restrict__ mW2,
                 const short* __restrict__ aW1b, const short* __restrict__ aW2,
                 const float* __restrict__ mb1, const float* __restrict__ mb2,
                 const float* __restrict__ ab1, const float* __restrict__ ab2,
                 short* __restrict__ msgatt, int M, int ntiles)
{
    __shared__ char HIDm[16384];
    __shared__ char HIDa[16384];
    const int tid = threadIdx.x, l = tid & 63, w = tid >> 6;
    int q = ntiles >> 3, r = ntiles & 7;
    int xcd = blockIdx.x & 7, o = blockIdx.x >> 3;
    int tile = (xcd < r ? xcd * (q + 1) : r * (q + 1) + (xcd - r) * q) + o;
    const int pb = tile * 64;

    const char* erow[4];
    int dstv[4];
    s16x8 psv[2][4];
    {
#pragma unroll
        for (int n = 0; n < 4; ++n) {
            int pos = pb + 16 * n + (l & 15); if (pos >= M) pos = M - 1;
            int sv = srcs[pos];
            dstv[n] = dsts[pos];
            erow[n] = (const char*)(efc + (size_t)pos * 128);
#pragma unroll
            for (int mt = 0; mt < 2; ++mt) {
                int off = 2 * (32 * w + 16 * mt + ((l >> 4) << 2));
                psv[mt][n] = *(const s16x8*)(proj + (size_t)sv * 256 + off);
            }
        }
    }

    f32x4 accm[2][4] = {}, acca[2][4] = {};
#pragma unroll
    for (int ks = 0; ks < 4; ++ks) {
        int koff = ks * 32 + (l >> 4) * 8;
        bf16x8 am0 = ldA(mW1b, 128, 32 * w + (l & 15), koff);
        bf16x8 am1 = ldA(mW1b, 128, 32 * w + 16 + (l & 15), koff);
        bf16x8 aa0 = ldA(aW1b, 128, 32 * w + (l & 15), koff);
        bf16x8 aa1 = ldA(aW1b, 128, 32 * w + 16 + (l & 15), koff);
#pragma unroll
        for (int n = 0; n < 4; ++n) {
            bf16x8 b = *(const bf16x8*)(erow[n] + koff * 2);
            accm[0][n] = MFMA(am0, b, accm[0][n]);
            accm[1][n] = MFMA(am1, b, accm[1][n]);
            acca[0][n] = MFMA(aa0, b, acca[0][n]);
            acca[1][n] = MFMA(aa1, b, acca[1][n]);
        }
    }
#pragma unroll
    for (int mt = 0; mt < 2; ++mt) {
        int h0 = 32 * w + 16 * mt + ((l >> 4) << 2);
        float4 bm = *(const float4*)&mb1[h0];
        float4 ba = *(const float4*)&ab1[h0];
        float bmv[4] = {bm.x, bm.y, bm.z, bm.w};
        float bav[4] = {ba.x, ba.y, ba.z, ba.w};
#pragma unroll
        for (int n = 0; n < 4; ++n) {
            s16x8 ps = psv[mt][n];
            s16x8 pd = *(const s16x8*)(proj + (size_t)dstv[n] * 256 + 2 * h0);
            f32x4 vm = accm[mt][n], va = acca[mt][n];
            s16x4 sm, sa;
#pragma unroll
            for (int qq = 0; qq < 4; ++qq) {
                float m_ = vm[qq] + bmv[qq] + bf2f((unsigned short)ps[qq])
                           - bf2f((unsigned short)pd[qq]);
                float a_ = va[qq] + bav[qq] + bf2f((unsigned short)ps[qq + 4])
                           - bf2f((unsigned short)pd[qq + 4]);
                sm[qq] = f2bf(fmaxf(m_, 0.f));
                sa[qq] = f2bf(fmaxf(a_, 0.f));
            }
            hid_write(HIDm, h0, 16 * n + (l & 15), sm);
            hid_write(HIDa, h0, 16 * n + (l & 15), sa);
        }
    }
    __syncthreads();

    f32x4 acc2m[2][4] = {}, acc2a[2][4] = {};
#pragma unroll
    for (int ks = 0; ks < 4; ++ks) {
        int koff = ks * 32 + (l >> 4) * 8;
        bf16x8 wm0 = ldA(mW2, 128, 32 * w + (l & 15), koff);
        bf16x8 wm1 = ldA(mW2, 128, 32 * w + 16 + (l & 15), koff);
        bf16x8 wa0 = ldA(aW2, 128, 32 * w + (l & 15), koff);
        bf16x8 wa1 = ldA(aW2, 128, 32 * w + 16 + (l & 15), koff);
#pragma unroll
        for (int n = 0; n < 4; ++n) {
            bf16x8 bm = ld_swz(HIDm, 16 * n + (l & 15), ks * 4 + (l >> 4));
            bf16x8 ba = ld_swz(HIDa, 16 * n + (l & 15), ks * 4 + (l >> 4));
            acc2m[0][n] = MFMA(wm0, bm, acc2m[0][n]);
            acc2m[1][n] = MFMA(wm1, bm, acc2m[1][n]);
            acc2a[0][n] = MFMA(wa0, ba, acc2a[0][n]);
            acc2a[1][n] = MFMA(wa1, ba, acc2a[1][n]);
        }
    }
    __syncthreads();
#pragma unroll
    for (int mt = 0; mt < 2; ++mt) {
        int c0 = 32 * w + 16 * mt + ((l >> 4) << 2);
        float4 bm2 = *(const float4*)&mb2[c0];
        float4 ba2 = *(const float4*)&ab2[c0];
#pragma unroll
        for (int n = 0; n < 4; ++n) {
            f32x4 m_ = acc2m[mt][n], a_ = acc2a[mt][n];
            float o0 = (m_[0] + bm2.x) / (1.f + expf(-(a_[0] + ba2.x)));
            float o1 = (m_[1] + bm2.y) / (1.f + expf(-(a_[1] + ba2.y)));
            float o2 = (m_[2] + bm2.z) / (1.f + expf(-(a_[2] + ba2.z)));
            float o3 = (m_[3] + bm2.w) / (1.f + expf(-(a_[3] + ba2.w)));
            s16x4 s4;
            s4[0] = f2bf(o0); s4[1] = f2bf(o1); s4[2] = f2bf(o2); s4[3] = f2bf(o3);
            hid_write(HIDm, c0, 16 * n + (l & 15), s4);
        }
    }
    __syncthreads();
#pragma unroll
    for (int p2 = 0; p2 < 4; ++p2) {
        int row = p2 * 16 + (tid >> 4);
        int pos = pb + row;
        if (pos < M) {
            bf16x8 v = ld_swz(HIDm, row, tid & 15);
            *(s16x8*)(msgatt + (size_t)pos * 128 + (tid & 15) * 8) =
                __builtin_bit_cast(s16x8, v);
        }
    }
}

// ---------------------------------------------------------------------------
// mlp_loss (R10 hybrid — measured best): 64 edges/block, sequential passes,
// shfl-reduced loss accumulation + ballot counts.
// ---------------------------------------------------------------------------
__global__ __launch_bounds__(256, 4)
void mlp_loss(const short* __restrict__ sP, const int* __restrict__ gidx,
              const float* __restrict__ label, const int* __restrict__ sg,
              const short* __restrict__ thW1, const short* __restrict__ thW2,
              const short* __restrict__ thW3,
              const float* __restrict__ thb1, const float* __restrict__ thb2,
              const float* __restrict__ thb3,
              const short* __restrict__ alW1, const short* __restrict__ alW2,
              const short* __restrict__ alW3,
              const float* __restrict__ alb1, const float* __restrict__ alb2,
              const float* __restrict__ alb3,
              float* __restrict__ radj, float* __restrict__ rla,
              float* __restrict__ cntS, int E, int S)
{
    __shared__ char D2T[16384];
    __shared__ char HID[16384];
    __shared__ float sacc[2][2][20];
    __shared__ float scnt[2];
    __shared__ int sbase;
    const int tid = threadIdx.x, l = tid & 63, w = tid >> 6;
    const int eb = blockIdx.x * 64;

    if (tid == 0) sbase = sg[eb];
    if (tid < 80) sacc[tid / 40][(tid / 20) & 1][tid % 20] = 0.f;

    if (w == 0) {
        int e = eb + l;
        bool valid = e < E;
        int lsv = valid ? sg[e] - sg[eb] : -1;
        unsigned long long m0 = __ballot(lsv == 0);
        unsigned long long m1 = __ballot(lsv == 1);
        if (l == 0) { scnt[0] = (float)__popcll(m0); scnt[1] = (float)__popcll(m1); }
    }

    for (int i = tid; i < 64 * 16; i += 256) {
        int row = i >> 4, u = i & 15;
        int e = eb + row; if (e >= E) e = E - 1;
        int2 ab = *(const int2*)&gidx[2 * (size_t)e];
        s16x8 x = *(const s16x8*)(sP + (size_t)ab.x * 128 + u * 8);
        s16x8 y = *(const s16x8*)(sP + (size_t)ab.y * 128 + u * 8);
        s16x8 d;
#pragma unroll
        for (int j = 0; j < 8; ++j)
            d[j] = f2bf(bf2f((unsigned short)x[j]) - bf2f((unsigned short)y[j]));
        *(s16x8*)(D2T + row * 256 + ((u ^ (row & 7)) << 4)) = d;
    }
    __syncthreads();

#pragma unroll 1
    for (int pass = 0; pass < 2; ++pass) {
        const short* W1 = pass ? alW1 : thW1;
        const short* W2 = pass ? alW2 : thW2;
        const short* W3 = pass ? alW3 : thW3;
        const float* b1 = pass ? alb1 : thb1;
        const float* b2 = pass ? alb2 : thb2;
        const float* b3 = pass ? alb3 : thb3;

        f32x4 acc[2][4] = {};
#pragma unroll
        for (int ks = 0; ks < 4; ++ks) {
            int koff = ks * 32 + (l >> 4) * 8;
            bf16x8 a0 = ldA(W1, 128, 32 * w + (l & 15), koff);
            bf16x8 a1 = ldA(W1, 128, 32 * w + 16 + (l & 15), koff);
#pragma unroll
            for (int n = 0; n < 4; ++n) {
                bf16x8 b = ld_swz(D2T, 16 * n + (l & 15), ks * 4 + (l >> 4));
                acc[0][n] = MFMA(a0, b, acc[0][n]);
                acc[1][n] = MFMA(a1, b, acc[1][n]);
            }
        }
        __syncthreads();
#pragma unroll
        for (int mt = 0; mt < 2; ++mt) {
            int h0 = 32 * w + 16 * mt + ((l >> 4) << 2);
            float4 bv = *(const float4*)&b1[h0];
#pragma unroll
            for (int n = 0; n < 4; ++n) {
                f32x4 v = acc[mt][n];
                s16x4 s4;
                s4[0] = f2bf(fmaxf(v[0] + bv.x, 0.f));
                s4[1] = f2bf(fmaxf(v[1] + bv.y, 0.f));
                s4[2] = f2bf(fmaxf(v[2] + bv.z, 0.f));
                s4[3] = f2bf(fmaxf(v[3] + bv.w, 0.f));
                hid_write(HID, h0, 16 * n + (l & 15), s4);
            }
        }
        __syncthreads();
        f32x4 acc2[2][4] = {};
#pragma unroll
        for (int ks = 0; ks < 4; ++ks) {
            int koff = ks * 32 + (l >> 4) * 8;
            bf16x8 a0 = ldA(W2, 128, 32 * w + (l & 15), koff);
            bf16x8 a1 = ldA(W2, 128, 32 * w + 16 + (l & 15), koff);
#pragma unroll
            for (int n = 0; n < 4; ++n) {
                bf16x8 b = ld_swz(HID, 16 * n + (l & 15), ks * 4 + (l >> 4));
                acc2[0][n] = MFMA(a0, b, acc2[0][n]);
                acc2[1][n] = MFMA(a1, b, acc2[1][n]);
            }
        }
        __syncthreads();
#pragma unroll
        for (int mt = 0; mt < 2; ++mt) {
            int h0 = 32 * w + 16 * mt + ((l >> 4) << 2);
            float4 bv = *(const float4*)&b2[h0];
#pragma unroll
            for (int n = 0; n < 4; ++n) {
                f32x4 v = acc2[mt][n];
                s16x4 s4;
                s4[0] = f2bf(fmaxf(v[0] + bv.x, 0.f));
                s4[1] = f2bf(fmaxf(v[1] + bv.y, 0.f));
                s4[2] = f2bf(fmaxf(v[2] + bv.z, 0.f));
                s4[3] = f2bf(fmaxf(v[3] + bv.w, 0.f));
                hid_write(HID, h0, 16 * n + (l & 15), s4);
            }
        }
        __syncthreads();
        f32x4 acc3[2] = {};
#pragma unroll
        for (int ks = 0; ks < 4; ++ks) {
            int koff = ks * 32 + (l >> 4) * 8;
            bf16x8 a0 = ldA(W3, 128, (l & 15), koff);
            bf16x8 a1 = ldA(W3, 128, 16 + (l & 15), koff);
            bf16x8 b = ld_swz(HID, 16 * w + (l & 15), ks * 4 + (l >> 4));
            acc3[0] = MFMA(a0, b, acc3[0]);
            acc3[1] = MFMA(a1, b, acc3[1]);
        }
        {
            int e = eb + 16 * w + (l & 15);
            bool val = e < E;
            float lsf = val ? (float)(sg[e] - sbase) : 0.f;
            float yv = (pass == 0 && val) ? label[e] : 0.f;
#pragma unroll
            for (int mt = 0; mt < 2; ++mt) {
#pragma unroll
                for (int qq = 0; qq < 4; ++qq) {
                    int k = 16 * mt + ((l >> 4) << 2) + qq;
                    bool kok = k < 20;
                    float bk = kok ? b3[k] : 0.f;
                    float vv = 0.f;
                    if (val && kok) {
                        float t = acc3[mt][qq] + bk;
                        if (pass == 0) {
                            float sp = fmaxf(-t, 0.f) + log1pf(expf(-fabsf(t)));
                            vv = sp + (1.f - yv) * t;
                        } else {
                            vv = t;
                        }
                    }
                    float vA = vv * (1.f - lsf), vB = vv * lsf;
                    vA += __shfl_xor(vA, 1); vB += __shfl_xor(vB, 1);
                    vA += __shfl_xor(vA, 2); vB += __shfl_xor(vB, 2);
                    vA += __shfl_xor(vA, 4); vB += __shfl_xor(vB, 4);
                    vA += __shfl_xor(vA, 8); vB += __shfl_xor(vB, 8);
                    if ((l & 15) == 0 && kok) {
                        atomicAdd(&sacc[pass][0][k], vA);
                        if (vB != 0.f) atomicAdd(&sacc[pass][1][k], vB);
                    }
                }
            }
        }
    }
    __syncthreads();
    if (tid < 40) {
        int ls = tid / 20, k = tid % 20;
        int s = sbase + ls;
        if (s < S) {
            float v  = sacc[0][ls][k];
            float v2 = sacc[1][ls][k];
            if (v  != 0.f) atomicAdd(&radj[s * 20 + k], v);
            if (v2 != 0.f) atomicAdd(&rla[s * 20 + k], v2);
        }
    }
    if (tid < 2) {
        int s = sbase + tid;
        if (s < S && scnt[tid] != 0.f) atomicAdd(&cntS[s], scnt[tid]);
    }
}

// ---------------------------------------------------------------------------
// CSR build + gathers
// ---------------------------------------------------------------------------
__global__ void csr_count(const int* __restrict__ edge, int* __restrict__ cnt, int M) {
    int e = blockIdx.x * 256 + threadIdx.x;
    if (e < M) atomicAdd(&cnt[edge[2 * (size_t)e + 1]], 1);
}

__global__ void csr_scan(const int* __restrict__ cnt, int* __restrict__ rowptr,
                         int* __restrict__ wofs, int N)
{
    __shared__ int part[1024];
    int t = threadIdx.x;
    int chunk = (N + 1023) / 1024;
    int b0 = t * chunk, b1 = b0 + chunk; if (b1 > N) b1 = N; if (b0 > N) b0 = N;
    int s = 0;
    for (int i = b0; i < b1; ++i) s += cnt[i];
    part[t] = s;
    __syncthreads();
    for (int off = 1; off < 1024; off <<= 1) {
        int v = (t >= off) ? part[t - off] : 0;
        __syncthreads();
        part[t] += v;
        __syncthreads();
    }
    int run = (t ? part[t - 1] : 0);
    for (int i = b0; i < b1; ++i) { rowptr[i] = run; wofs[i] = run; run += cnt[i]; }
    if (t == 1023) rowptr[N] = run;
}

__global__ void csr_scatter2(const int* __restrict__ edge, int* __restrict__ wofs,
                             int* __restrict__ eidx, int* __restrict__ srcs,
                             int* __restrict__ dsts, int M)
{
    int e = blockIdx.x * 256 + threadIdx.x;
    if (e < M) {
        int2 sd = *(const int2*)&edge[2 * (size_t)e];
        int p = atomicAdd(&wofs[sd.y], 1);
        eidx[p] = e; srcs[p] = sd.x; dsts[p] = sd.y;
    }
}

__global__ void ef_gather(const float* __restrict__ ef, const int* __restrict__ eidx,
                          short* __restrict__ efc, int M)
{
    long i = (long)blockIdx.x * 256 + threadIdx.x;
    if (i >= (long)M * 16) return;
    int p = (int)(i >> 4), u = (int)(i & 15);
    int e = eidx[p];
    const float* sp = ef + (size_t)e * 128 + u * 8;
    float4 a = *(const float4*)sp, b = *(const float4*)(sp + 4);
    s16x8 s;
    s[0] = f2bf(a.x); s[1] = f2bf(a.y); s[2] = f2bf(a.z); s[3] = f2bf(a.w);
    s[4] = f2bf(b.x); s[5] = f2bf(b.y); s[6] = f2bf(b.z); s[7] = f2bf(b.w);
    *(s16x8*)(efc + (size_t)p * 128 + u * 8) = s;
}

// ---------------------------------------------------------------------------
__global__ void final_kernel(const float* __restrict__ radj, const float* __restrict__ rla,
                             const float* __restrict__ cnt, const int* __restrict__ bc_idx,
                             float* __restrict__ out)
{
    __shared__ float bcl[16], bcc[16];
    const int s = threadIdx.x;
    if (s < 16) { bcl[s] = 0.f; bcc[s] = 0.f; }
    __syncthreads();
    float c = cnt[s];
    float x[20];
    float mx = -1e30f;
#pragma unroll
    for (int k = 0; k < 20; ++k) { x[k] = rla[s * 20 + k] / c; mx = fmaxf(mx, x[k]); }
    float se = 0.f;
#pragma unroll
    for (int k = 0; k < 20; ++k) se += expf(x[k] - mx);
    float lse = mx + logf(se);
    float t[20];
    float m2 = -1e30f;
#pragma unroll
    for (int k = 0; k < 20; ++k) { t[k] = -radj[s * 20 + k] + x[k] - lse; m2 = fmaxf(m2, t[k]); }
    float s2 = 0.f;
#pragma unroll
    for (int k = 0; k < 20; ++k) s2 += expf(t[k] - m2);
    float lp = m2 + logf(s2);
    atomicAdd(&bcl[bc_idx[s]], lp);
    atomicAdd(&bcc[bc_idx[s]], c);
    __syncthreads();
    if (s == 0) {
        float a = 0.f;
        for (int b = 0; b < 16; ++b) a += bcl[b] / bcc[b];
        out[0] = -a / 16.f;
    }
}

// ---------------------------------------------------------------------------
extern "C" void kernel_launch(void* const* d_in, const int* in_sizes, int n_in,
                              void* d_out, int out_size, void* d_ws, size_t ws_size,
                              hipStream_t stream)
{
    const float* node_feat = (const float*)d_in[0];
    const int*   edge      = (const int*)  d_in[1];
    const float* edge_feat = (const float*)d_in[2];
    const int*   gnn_idx   = (const int*)  d_in[3];
    const float* label     = (const float*)d_in[4];
    const int*   sg_idx    = (const int*)  d_in[5];
    const int*   bc_idx    = (const int*)  d_in[6];
    const float* dec_W  = (const float*)d_in[7];
    const float* dec_b  = (const float*)d_in[8];
    const float* msg_W1 = (const float*)d_in[9];
    const float* msg_b1 = (const float*)d_in[10];
    const float* msg_W2 = (const float*)d_in[11];
    const float* msg_b2 = (const float*)d_in[12];
    const float* att_W1 = (const float*)d_in[13];
    const float* att_b1 = (const float*)d_in[14];
    const float* att_W2 = (const float*)d_in[15];
    const float* att_b2 = (const float*)d_in[16];
    const float* gru_Wih = (const float*)d_in[17];
    const float* gru_bih = (const float*)d_in[18];
    const float* gru_Whh = (const float*)d_in[19];
    const float* gru_bhh = (const float*)d_in[20];
    const float* th_W1 = (const float*)d_in[21];
    const float* th_b1 = (const float*)d_in[22];
    const float* th_W2 = (const float*)d_in[23];
    const float* th_b2 = (const float*)d_in[24];
    const float* th_W3 = (const float*)d_in[25];
    const float* th_b3 = (const float*)d_in[26];
    const float* al_W1 = (const float*)d_in[27];
    const float* al_b1 = (const float*)d_in[28];
    const float* al_W2 = (const float*)d_in[29];
    const float* al_b2 = (const float*)d_in[30];
    const float* al_W3 = (const float*)d_in[31];
    const float* al_b3 = (const float*)d_in[32];

    const int N = in_sizes[0] / 512;
    const int M = in_sizes[1] / 2;
    const int E = in_sizes[3] / 2;
    const int S = in_sizes[6];

    size_t off = 0;
    auto alloc = [&](size_t bytes) {
        char* p = (char*)d_ws + off;
        off += (bytes + 255) & ~(size_t)255;
        return p;
    };
    // bf16 weight slabs
    short* decWb  = (short*)alloc((size_t)128 * 512 * 2);
    short* projWb = (short*)alloc((size_t)3 * 256 * 128 * 2);
    short* mW1bB  = (short*)alloc((size_t)3 * 128 * 128 * 2);
    short* aW1bB  = (short*)alloc((size_t)3 * 128 * 128 * 2);
    short* mW2B   = (short*)alloc((size_t)3 * 128 * 128 * 2);
    short* aW2B   = (short*)alloc((size_t)3 * 128 * 128 * 2);
    short* gihB   = (short*)alloc((size_t)3 * 384 * 128 * 2);
    short* ghhB   = (short*)alloc((size_t)3 * 384 * 128 * 2);
    short* thW1B  = (short*)alloc((size_t)128 * 128 * 2);
    short* thW2B  = (short*)alloc((size_t)128 * 128 * 2);
    short* thW3B  = (short*)alloc((size_t)32 * 128 * 2);
    short* alW1B  = (short*)alloc((size_t)128 * 128 * 2);
    short* alW2B  = (short*)alloc((size_t)128 * 128 * 2);
    short* alW3B  = (short*)alloc((size_t)32 * 128 * 2);
    // activations
    short* sA     = (short*)alloc((size_t)N * 128 * 2);
    short* sB     = (short*)alloc((size_t)N * 128 * 2);
    short* sP     = (short*)alloc((size_t)N * 128 * 2);
    short* efc    = (short*)alloc((size_t)M * 128 * 2);
    short* msgatt = (short*)alloc((size_t)M * 128 * 2);
    short* proj   = (short*)alloc((size_t)N * 256 * 2);
    int*   cntN   = (int*)  alloc((size_t)N * 4);
    int*   wofs   = (int*)  alloc((size_t)N * 4);
    int*   rowptr = (int*)  alloc((size_t)(N + 1) * 4);
    int*   eidx   = (int*)  alloc((size_t)M * 4);
    int*   srcs   = (int*)  alloc((size_t)M * 4);
    int*   dsts   = (int*)  alloc((size_t)M * 4);
    float* radj   = (float*)alloc((size_t)S * 20 * 4);
    float* rla    = (float*)alloc((size_t)S * 20 * 4);
    float* cntS   = (float*)alloc((size_t)S * 4);

    // ---- prepack descriptor table ----
    PrepackArgs pa;
    int ei = 0;
    auto add = [&](const float* s, short* d, int stride, int rows, int rowsTot, int cols) {
        pa.src[ei] = s; pa.dst[ei] = d; pa.stride[ei] = stride;
        pa.rows[ei] = rows; pa.rowsTot[ei] = rowsTot; pa.cols[ei] = cols; ++ei;
    };
    add(dec_W, decWb, 512, 128, 128, 512);
    for (int l = 0; l < 3; ++l) {
        add(msg_W1 + (size_t)l * 128 * 256,       projWb + (size_t)l * 256 * 128,          256, 128, 128, 128);
        add(att_W1 + (size_t)l * 128 * 256,       projWb + (size_t)l * 256 * 128 + 16384,  256, 128, 128, 128);
        add(msg_W1 + (size_t)l * 128 * 256 + 128, mW1bB + (size_t)l * 16384,               256, 128, 128, 128);
        add(att_W1 + (size_t)l * 128 * 256 + 128, aW1bB + (size_t)l * 16384,               256, 128, 128, 128);
        add(msg_W2 + (size_t)l * 16384,           mW2B + (size_t)l * 16384,                128, 128, 128, 128);
        add(att_W2 + (size_t)l * 16384,           aW2B + (size_t)l * 16384,                128, 128, 128, 128);
        add(gru_Wih + (size_t)l * 49152,          gihB + (size_t)l * 49152,                128, 384, 384, 128);
        add(gru_Whh + (size_t)l * 49152,          ghhB + (size_t)l * 49152,                128, 384, 384, 128);
    }
    add(th_W1, thW1B, 128, 128, 128, 128);
    add(th_W2, thW2B, 128, 128, 128, 128);
    add(th_W3, thW3B, 128, 20, 32, 128);
    add(al_W1, alW1B, 128, 128, 128, 128);
    add(al_W2, alW2B, 128, 128, 128, 128);
    add(al_W3, alW3B, 128, 20, 32, 128);

    const dim3 blk(256);
    const int gN64 = (N + 63) / 64;
    const int gE64 = (E + 63) / 64;
    const int gMt  = (M + 255) / 256;
    const int ntilesM = (M + 63) / 64;

    hipMemsetAsync(radj, 0, (size_t)(S * 20 * 2 + S) * 4, stream);
    hipMemsetAsync(cntN, 0, (size_t)N * 4, stream);

    prepack<<<dim3(384, NPACK), dim3(64), 0, stream>>>(pa);

    csr_count   <<<gMt, blk, 0, stream>>>(edge, cntN, M);
    csr_scan    <<<1, 1024, 0, stream>>>(cntN, rowptr, wofs, N);
    csr_scatter2<<<gMt, blk, 0, stream>>>(edge, wofs, eidx, srcs, dsts, M);
    ef_gather   <<<(int)(((long)M * 16 + 255) / 256), blk, 0, stream>>>(edge_feat, eidx, efc, M);

    // decoder + proj0
    dec_proj<<<gN64, blk, 0, stream>>>(node_feat, N, decWb, dec_b, projWb, sA, proj);

    short* bufs[2] = { sA, sB };
    for (int l = 0; l < 3; ++l) {
        short* sin  = bufs[l & 1];
        short* sout = (l == 2) ? sP : bufs[(l + 1) & 1];
        edge_fused2<<<ntilesM, blk, 0, stream>>>(efc, srcs, dsts, proj,
            mW1bB + (size_t)l * 16384, mW2B + (size_t)l * 16384,
            aW1bB + (size_t)l * 16384, aW2B + (size_t)l * 16384,
            msg_b1 + l * 128, msg_b2 + l * 128,
            att_b1 + l * 128, att_b2 + l * 128,
            msgatt, M, ntilesM);
        if (l < 2) {
            node_fused4<1><<<gN64, blk, 0, stream>>>(msgatt, rowptr, sin,
                gihB + (size_t)l * 49152, ghhB + (size_t)l * 49152,
                gru_bih + l * 384, gru_bhh + l * 384,
                projWb + (size_t)(l + 1) * 256 * 128, sout, proj, N);
        } else {
            node_fused4<0><<<gN64, blk, 0, stream>>>(msgatt, rowptr, sin,
                gihB + (size_t)l * 49152, ghhB + (size_t)l * 49152,
                gru_bih + l * 384, gru_bhh + l * 384,
                nullptr, sout, nullptr, N);
        }
    }

    mlp_loss<<<gE64, blk, 0, stream>>>(sP, gnn_idx, label, sg_idx,
        thW1B, thW2B, thW3B, th_b1, th_b2, th_b3,
        alW1B, alW2B, alW3B, al_b1, al_b2, al_b3,
        radj, rla, cntS, E, S);
    final_kernel<<<1, S, 0, stream>>>(radj, rla, cntS, bc_idx, (float*)d_out);
}